// Round 5
// baseline (16693.614 us; speedup 1.0000x reference)
//
#include <hip/hip_runtime.h>
#include <hip/hip_bf16.h>
#include <math.h>

// ---------------- problem constants ----------------
#define TT   128      // timesteps
#define BB   128      // batch
#define UU   512      // LSTM units
#define EMBD 300      // embedding dim
#define EMBP 320      // padded embedding dim (multiple of 32 for MFMA K)
#define NBLK 256
#define NTHR 256

using bf16x8 = __attribute__((ext_vector_type(8))) short;
using f32x4  = __attribute__((ext_vector_type(4))) float;

// ---- fallback scratch pool (allocated at dlopen, outside graph capture) ----
#define NEED_WS 78119168ull
static void* g_pool = nullptr;
__attribute__((constructor)) static void alloc_pool() {
    if (hipMalloc(&g_pool, 80ull * 1024ull * 1024ull) != hipSuccess) g_pool = nullptr;
}

__device__ __forceinline__ float b2f(unsigned short u) {
    union { unsigned int i; float f; } v; v.i = ((unsigned int)u) << 16; return v.f;
}
__device__ __forceinline__ unsigned short f2b(float f) {
    union { unsigned int i; float f; } v; v.f = f;
    unsigned int i = v.i;
    return (unsigned short)((i + 0x7fffu + ((i >> 16) & 1u)) >> 16);  // RNE
}
// dtype-polymorphic loads: f32 flag selects fp32 or bf16 source interpretation
__device__ __forceinline__ unsigned short ld_bf(const void* p, size_t i, int f32) {
    return f32 ? f2b(((const float*)p)[i]) : ((const unsigned short*)p)[i];
}
__device__ __forceinline__ float ld_f(const void* p, size_t i, int f32) {
    return f32 ? ((const float*)p)[i] : b2f(((const unsigned short*)p)[i]);
}
__device__ __forceinline__ float clampz(float x) {
    return fminf(fmaxf(x, -60.0f), 60.0f);
}
__device__ __forceinline__ float sigm(float x)  { return 1.0f / (1.0f + __expf(-x)); }
__device__ __forceinline__ float ssign(float x) { return x / (1.0f + fabsf(x)); }

// emb ~ N(0,1): fp32 words have exponent ~[96,159]; bf16-packed pairs read as
// fp32 have exponent >= ~224. Uniform across all blocks -> no sync needed.
__device__ __forceinline__ int detect_f32(const void* emb) {
    const unsigned int* w = (const unsigned int*)emb;
    int cnt = 0;
    #pragma unroll
    for (int i = 0; i < 64; ++i) {
        unsigned int e = (w[i] >> 23) & 0xFFu;
        cnt += (e >= 96u && e <= 159u) ? 1 : 0;
    }
    return cnt >= 48;
}

struct P {
    const int* ids;
    const void* emb;
    const void* Wm[2][3];   // [dir][layer] input weights  [din,2048]
    const void* Um[2][3];   // [dir][layer] recurrent      [512,2048]
    const void* bm[2][3];   // [dir][layer] bias           [2048]
    const void *d0W, *d0b;
    const void *bn_gamma, *bn_beta, *bn_mean, *bn_var;
    const void *alpha, *d1W, *d1b;
    unsigned short* X;      // [TT][BB][EMBP] bf16
    unsigned short* H;      // [2 slots][2 dirs][TT][BB][UU] bf16
    float* hf;              // [2][BB][UU] final top-layer h, fp32
    unsigned int* bar;      // [0]=counter [1]=generation
    float* out;             // [BB][7] fp32  <-- output is float32 (forensically established)
};

// device-scope sense(generation)-reversing grid barrier.
__device__ __forceinline__ void gsync(unsigned int* bar) {
    __syncthreads();
    if (threadIdx.x == 0) {
        __threadfence();
        unsigned int g = __hip_atomic_load(&bar[1], __ATOMIC_ACQUIRE, __HIP_MEMORY_SCOPE_AGENT);
        unsigned int a = __hip_atomic_fetch_add(&bar[0], 1u, __ATOMIC_ACQ_REL, __HIP_MEMORY_SCOPE_AGENT);
        if (a == NBLK - 1u) {
            __hip_atomic_store(&bar[0], 0u, __ATOMIC_RELAXED, __HIP_MEMORY_SCOPE_AGENT);
            __hip_atomic_store(&bar[1], g + 1u, __ATOMIC_RELEASE, __HIP_MEMORY_SCOPE_AGENT);
        } else {
            while (__hip_atomic_load(&bar[1], __ATOMIC_ACQUIRE, __HIP_MEMORY_SCOPE_AGENT) == g) {
                __builtin_amdgcn_s_sleep(1);
            }
        }
        __threadfence();
    }
    __syncthreads();
}

__global__ __launch_bounds__(NTHR, 1) void bilstm_persistent(P p) {
    const int blk = blockIdx.x;
    const int tid = threadIdx.x;

    const int f32 = detect_f32(p.emb);   // uniform across grid

    __shared__ __align__(16) unsigned short Bt[16][1032];  // B panel [n][k] (33 KB)
    __shared__ __align__(16) float zld[128][17];           // z round-trip (8.7 KB)
    __shared__ float hact[256];
    __shared__ float lgts[8];

    // ---------------- phase 0: embedding gather (-> bf16 X, zero-padded) ----------------
    for (int rr = 0; rr < 64; ++rr) {
        int row = blk * 64 + rr;             // row = t*BB + b
        int t = row >> 7, b = row & 127;
        int id = p.ids[b * TT + t];
        unsigned short* xr = p.X + (size_t)row * EMBP;
        for (int k2 = tid; k2 < EMBP; k2 += NTHR)
            xr[k2] = (k2 < EMBD) ? ld_bf(p.emb, (size_t)id * EMBD + k2, f32)
                                 : (unsigned short)0;
    }
    gsync(p.bar);

    // block responsibilities: dir, 4 h-columns, full batch M=128
    const int dir = blk >> 7;
    const int j0  = (blk & 127) * 4;

    const int wv   = tid >> 6;               // wave 0..3
    const int lane = tid & 63;
    const int l15  = lane & 15;
    const int quad = lane >> 4;

    const int gr = tid >> 2;                 // gate thread: rows gr and gr+64
    const int gj = tid & 3;                  //   column j0+gj

    float c0 = 0.0f, c1 = 0.0f;              // cell state in registers

    const size_t seq = (size_t)TT * BB * UU;

    for (int l = 0; l < 3; ++l) {
        const int KW   = (l == 0) ? EMBD : UU;
        const int K1   = (l == 0) ? EMBP : UU;
        const int Ktot = K1 + UU;
        const void* Wmat = p.Wm[dir][l];
        const void* Umat = p.Um[dir][l];
        const void* bias = p.bm[dir][l];

        // ---- stage B panel (16 gate-columns) into LDS as bf16 ----
        {
            int n = tid >> 4, ks = tid & 15;
            int wcol = (n >> 2) * UU + j0 + (n & 3);   // gate*512 + j
            for (int k2 = ks; k2 < Ktot; k2 += 16) {
                unsigned short v;
                if (k2 < KW)      v = ld_bf(Wmat, (size_t)k2 * 2048 + wcol, f32);
                else if (k2 < K1) v = 0;
                else              v = ld_bf(Umat, (size_t)(k2 - K1) * 2048 + wcol, f32);
                Bt[n][k2] = v;
            }
        }
        const float bi  = ld_f(bias, 0 * UU + j0 + gj, f32);
        const float bf_ = ld_f(bias, 1 * UU + j0 + gj, f32);
        const float bg  = ld_f(bias, 2 * UU + j0 + gj, f32);
        const float bo  = ld_f(bias, 3 * UU + j0 + gj, f32);
        __syncthreads();

        const int s_write = (l == 1) ? 1 : 0;
        const int s_read  = (l == 1) ? 0 : 1;
        unsigned short*       Hl  = p.H + (size_t)(s_write * 2 + dir) * seq;
        const unsigned short* Hin = p.H + (size_t)(s_read  * 2 + dir) * seq;

        for (int t = 0; t < TT; ++t) {
            const unsigned short* A1;
            int sA1;
            if (l == 0) {
                int tx = dir ? (TT - 1 - t) : t;
                A1 = p.X + (size_t)tx * BB * EMBP;  sA1 = EMBP;
            } else {
                A1 = Hin + (size_t)t * BB * UU;     sA1 = UU;
            }
            const unsigned short* A2 = Hl + (size_t)(t > 0 ? t - 1 : 0) * BB * UU;
            const int kend = (t == 0) ? K1 : Ktot;   // t==0: h_prev == 0

            const int r0 = wv * 32 + l15;
            const int r1 = r0 + 16;

            f32x4 a0 = {0.f, 0.f, 0.f, 0.f};
            f32x4 a1 = {0.f, 0.f, 0.f, 0.f};
            #pragma unroll 4
            for (int kt = 0; kt < kend; kt += 32) {
                int k2 = kt + quad * 8;              // K1 % 32 == 0
                const unsigned short *ap0, *ap1;
                if (k2 < K1) {
                    ap0 = A1 + (size_t)r0 * sA1 + k2;
                    ap1 = A1 + (size_t)r1 * sA1 + k2;
                } else {
                    ap0 = A2 + (size_t)r0 * UU + (k2 - K1);
                    ap1 = A2 + (size_t)r1 * UU + (k2 - K1);
                }
                bf16x8 bv = *(const bf16x8*)&Bt[l15][k2];
                a0 = __builtin_amdgcn_mfma_f32_16x16x32_bf16(*(const bf16x8*)ap0, bv, a0, 0, 0, 0);
                a1 = __builtin_amdgcn_mfma_f32_16x16x32_bf16(*(const bf16x8*)ap1, bv, a1, 0, 0, 0);
            }
            // D layout: col = lane&15, row = quad*4 + reg  (m89-verified)
            #pragma unroll
            for (int r = 0; r < 4; ++r) {
                zld[wv * 32 +      quad * 4 + r][l15] = a0[r];
                zld[wv * 32 + 16 + quad * 4 + r][l15] = a1[r];
            }
            __syncthreads();

            // ---- gates (fp32, clamped), c in registers, h -> bf16 ----
            {
                float zi = clampz(zld[gr][ 0 + gj] + bi);
                float zf = clampz(zld[gr][ 4 + gj] + bf_);
                float zg = clampz(zld[gr][ 8 + gj] + bg);
                float zo = clampz(zld[gr][12 + gj] + bo);
                float cp = (t == 0) ? 0.0f : c0;
                float cn = sigm(zf) * cp + sigm(zi) * ssign(zg);
                c0 = cn;
                float h = sigm(zo) * ssign(cn);
                Hl[(size_t)t * BB * UU + (size_t)gr * UU + j0 + gj] = f2b(h);
                if (l == 2 && t == TT - 1)
                    p.hf[(size_t)dir * BB * UU + (size_t)gr * UU + j0 + gj] = h;

                int g2 = gr + 64;
                float zi2 = clampz(zld[g2][ 0 + gj] + bi);
                float zf2 = clampz(zld[g2][ 4 + gj] + bf_);
                float zg2 = clampz(zld[g2][ 8 + gj] + bg);
                float zo2 = clampz(zld[g2][12 + gj] + bo);
                float cp2 = (t == 0) ? 0.0f : c1;
                float cn2 = sigm(zf2) * cp2 + sigm(zi2) * ssign(zg2);
                c1 = cn2;
                float h2 = sigm(zo2) * ssign(cn2);
                Hl[(size_t)t * BB * UU + (size_t)g2 * UU + j0 + gj] = f2b(h2);
                if (l == 2 && t == TT - 1)
                    p.hf[(size_t)dir * BB * UU + (size_t)g2 * UU + j0 + gj] = h2;
            }
            gsync(p.bar);
        }
    }

    // ---------------- head: block b handles batch row b (all fp32) ----------------
    if (blk < BB) {
        const int b = blk;
        const float* h0 = p.hf + (size_t)b * UU;
        const float* h1 = p.hf + (size_t)BB * UU + (size_t)b * UU;
        float acc = ld_f(p.d0b, tid, f32);
        #pragma unroll 8
        for (int k = 0; k < UU; ++k) {
            float a = 0.5f * (h0[k] + h1[k]);
            acc = fmaf(a, ld_f(p.d0W, (size_t)k * 256 + tid, f32), acc);
        }
        acc = fminf(fmaxf(acc, -1e6f), 1e6f);
        float x = (acc - ld_f(p.bn_mean, tid, f32))
                  * rsqrtf(fmaxf(ld_f(p.bn_var, tid, f32), 0.0f) + 1e-3f)
                  * ld_f(p.bn_gamma, tid, f32) + ld_f(p.bn_beta, tid, f32);
        float al = ld_f(p.alpha, tid, f32);
        hact[tid] = (x > 0.f) ? x : al * x;
        __syncthreads();
        if (tid < 7) {
            float s = ld_f(p.d1b, tid, f32);
            #pragma unroll 8
            for (int k = 0; k < 256; ++k)
                s = fmaf(hact[k], ld_f(p.d1W, k * 7 + tid, f32), s);
            lgts[tid] = fminf(fmaxf(s, -1e6f), 1e6f);
        }
        __syncthreads();
        if (tid == 0) {
            float mx = lgts[0];
            for (int j = 1; j < 7; ++j) mx = fmaxf(mx, lgts[j]);
            float ex[7]; float sum = 0.f;
            for (int j = 0; j < 7; ++j) { ex[j] = __expf(lgts[j] - mx); sum += ex[j]; }
            float inv = 1.0f / sum;
            for (int j = 0; j < 7; ++j) p.out[b * 7 + j] = ex[j] * inv;   // fp32 store
        }
    }
}

extern "C" void kernel_launch(void* const* d_in, const int* in_sizes, int n_in,
                              void* d_out, int out_size, void* d_ws, size_t ws_size,
                              hipStream_t stream) {
    (void)in_sizes; (void)n_in; (void)out_size;

    P p;
    p.ids = (const int*)d_in[0];
    p.emb = d_in[1];
    for (int l = 0; l < 3; ++l) {
        p.Wm[0][l] = d_in[2 + l * 3];
        p.Um[0][l] = d_in[3 + l * 3];
        p.bm[0][l] = d_in[4 + l * 3];
        p.Wm[1][l] = d_in[11 + l * 3];
        p.Um[1][l] = d_in[12 + l * 3];
        p.bm[1][l] = d_in[13 + l * 3];
    }
    p.d0W      = d_in[20];
    p.d0b      = d_in[21];
    p.bn_gamma = d_in[22];
    p.bn_beta  = d_in[23];
    p.bn_mean  = d_in[24];
    p.bn_var   = d_in[25];
    p.alpha    = d_in[26];
    p.d1W      = d_in[27];
    p.d1b      = d_in[28];

    char* base = (ws_size >= NEED_WS || g_pool == nullptr) ? (char*)d_ws : (char*)g_pool;
    const size_t OFF_X  = 256;
    const size_t OFF_H  = OFF_X + (size_t)TT * BB * EMBP * 2;
    const size_t OFF_HF = OFF_H + (size_t)2 * 2 * TT * BB * UU * 2;
    p.bar = (unsigned int*)base;
    p.X   = (unsigned short*)(base + OFF_X);
    p.H   = (unsigned short*)(base + OFF_H);
    p.hf  = (float*)(base + OFF_HF);
    p.out = (float*)d_out;

    // only the barrier block needs zeroing; all other scratch is written
    // before it is read within this launch (poison-safe).
    hipMemsetAsync(base, 0, 256, stream);
    hipLaunchKernelGGL(bilstm_persistent, dim3(NBLK), dim3(NTHR), 0, stream, p);
}

// Round 6
// 9482.922 us; speedup vs baseline: 1.7604x; 1.7604x over previous
//
#include <hip/hip_runtime.h>
#include <hip/hip_bf16.h>
#include <math.h>

// ---------------- problem constants ----------------
#define TT   128      // timesteps
#define BB   128      // batch
#define UU   512      // LSTM units
#define EMBD 300      // embedding dim
#define EMBP 320      // padded embedding dim (multiple of 32 for MFMA K)
#define NBLK 256
#define NTHR 256

using bf16x8 = __attribute__((ext_vector_type(8))) short;
using f32x4  = __attribute__((ext_vector_type(4))) float;

// ---- fallback scratch pool (allocated at dlopen, outside graph capture) ----
#define NEED_WS 78123008ull
static void* g_pool = nullptr;
__attribute__((constructor)) static void alloc_pool() {
    if (hipMalloc(&g_pool, 80ull * 1024ull * 1024ull) != hipSuccess) g_pool = nullptr;
}

__device__ __forceinline__ float b2f(unsigned short u) {
    union { unsigned int i; float f; } v; v.i = ((unsigned int)u) << 16; return v.f;
}
__device__ __forceinline__ unsigned short f2b(float f) {
    union { unsigned int i; float f; } v; v.f = f;
    unsigned int i = v.i;
    return (unsigned short)((i + 0x7fffu + ((i >> 16) & 1u)) >> 16);  // RNE
}
// dtype-polymorphic loads: f32 flag selects fp32 or bf16 source interpretation
__device__ __forceinline__ unsigned short ld_bf(const void* p, size_t i, int f32) {
    return f32 ? f2b(((const float*)p)[i]) : ((const unsigned short*)p)[i];
}
__device__ __forceinline__ float ld_f(const void* p, size_t i, int f32) {
    return f32 ? ((const float*)p)[i] : b2f(((const unsigned short*)p)[i]);
}
__device__ __forceinline__ float clampz(float x) {
    return fminf(fmaxf(x, -60.0f), 60.0f);
}
__device__ __forceinline__ float sigm(float x)  { return 1.0f / (1.0f + __expf(-x)); }
__device__ __forceinline__ float ssign(float x) { return x / (1.0f + fabsf(x)); }

// emb ~ N(0,1): fp32 words have exponent ~[96,159]; bf16-packed pairs read as
// fp32 have huge exponents. Uniform across all blocks -> no sync needed.
__device__ __forceinline__ int detect_f32(const void* emb) {
    const unsigned int* w = (const unsigned int*)emb;
    int cnt = 0;
    #pragma unroll
    for (int i = 0; i < 64; ++i) {
        unsigned int e = (w[i] >> 23) & 0xFFu;
        cnt += (e >= 96u && e <= 159u) ? 1 : 0;
    }
    return cnt >= 48;
}

struct P {
    const int* ids;
    const void* emb;
    const void* Wm[2][3];   // [dir][layer] input weights  [din,2048]
    const void* Um[2][3];   // [dir][layer] recurrent      [512,2048]
    const void* bm[2][3];   // [dir][layer] bias           [2048]
    const void *d0W, *d0b;
    const void *bn_gamma, *bn_beta, *bn_mean, *bn_var;
    const void *alpha, *d1W, *d1b;
    unsigned short* X;      // [TT][BB][EMBP] bf16
    unsigned short* H;      // [2 slots][2 dirs][TT][BB][UU] bf16
    float* hf;              // [2][BB][UU] final top-layer h, fp32
    unsigned int* flags;    // [NBLK] per-block barrier generation flags
    float* out;             // [BB][7] fp32
};

// Contention-free grid barrier: per-block flag words (no shared-counter RMW
// serialization). Release: one __threadfence (L2 writeback; all waves' stores
// are already drained into L2 by the compiler's vmcnt(0) before s_barrier) +
// relaxed agent store to OWN flag. Wait: wave 0 scans all 256 flags with 4
// coalesced relaxed atomic loads/lane; acquire: one __threadfence (L2 inv)
// before the closing __syncthreads.
__device__ __forceinline__ void gsync(unsigned int* flags, unsigned int gen) {
    __syncthreads();
    if (threadIdx.x == 0) {
        __threadfence();   // push this XCD's dirty lines (incl. h stores) to LLC
        __hip_atomic_store(&flags[blockIdx.x], gen, __ATOMIC_RELAXED,
                           __HIP_MEMORY_SCOPE_AGENT);
    }
    if (threadIdx.x < 64) {
        const int i = threadIdx.x;
        for (;;) {
            unsigned int m0 = __hip_atomic_load(&flags[i      ], __ATOMIC_RELAXED, __HIP_MEMORY_SCOPE_AGENT);
            unsigned int m1 = __hip_atomic_load(&flags[i +  64], __ATOMIC_RELAXED, __HIP_MEMORY_SCOPE_AGENT);
            unsigned int m2 = __hip_atomic_load(&flags[i + 128], __ATOMIC_RELAXED, __HIP_MEMORY_SCOPE_AGENT);
            unsigned int m3 = __hip_atomic_load(&flags[i + 192], __ATOMIC_RELAXED, __HIP_MEMORY_SCOPE_AGENT);
            bool ok = (m0 >= gen) && (m1 >= gen) && (m2 >= gen) && (m3 >= gen);
            if (__all(ok)) break;
            __builtin_amdgcn_s_sleep(1);
        }
        __threadfence();   // invalidate stale L2 lines before consuming fresh data
    }
    __syncthreads();
}

__global__ __launch_bounds__(NTHR, 1) void bilstm_persistent(P p) {
    const int blk = blockIdx.x;
    const int tid = threadIdx.x;

    const int f32 = detect_f32(p.emb);   // uniform across grid
    unsigned int gen = 0;                // barrier generation counter

    __shared__ __align__(16) unsigned short Bt[16][1032];  // B panel [n][k] (33 KB)
    __shared__ __align__(16) float zld[128][17];           // z round-trip (8.7 KB)
    __shared__ float hact[256];
    __shared__ float lgts[8];

    // ---------------- phase 0: embedding gather (-> bf16 X, zero-padded) ----------------
    for (int rr = 0; rr < 64; ++rr) {
        int row = blk * 64 + rr;             // row = t*BB + b
        int t = row >> 7, b = row & 127;
        int id = p.ids[b * TT + t];
        unsigned short* xr = p.X + (size_t)row * EMBP;
        for (int k2 = tid; k2 < EMBP; k2 += NTHR)
            xr[k2] = (k2 < EMBD) ? ld_bf(p.emb, (size_t)id * EMBD + k2, f32)
                                 : (unsigned short)0;
    }
    gsync(p.flags, ++gen);

    // block responsibilities: dir, 4 h-columns, full batch M=128
    const int dir = blk >> 7;
    const int j0  = (blk & 127) * 4;

    const int wv   = tid >> 6;               // wave 0..3
    const int lane = tid & 63;
    const int l15  = lane & 15;
    const int quad = lane >> 4;

    const int gr = tid >> 2;                 // gate thread: rows gr and gr+64
    const int gj = tid & 3;                  //   column j0+gj

    float c0 = 0.0f, c1 = 0.0f;              // cell state in registers

    const size_t seq = (size_t)TT * BB * UU;

    for (int l = 0; l < 3; ++l) {
        const int KW   = (l == 0) ? EMBD : UU;
        const int K1   = (l == 0) ? EMBP : UU;
        const int Ktot = K1 + UU;
        const void* Wmat = p.Wm[dir][l];
        const void* Umat = p.Um[dir][l];
        const void* bias = p.bm[dir][l];

        // ---- stage B panel (16 gate-columns) into LDS as bf16 ----
        {
            int n = tid >> 4, ks = tid & 15;
            int wcol = (n >> 2) * UU + j0 + (n & 3);   // gate*512 + j
            for (int k2 = ks; k2 < Ktot; k2 += 16) {
                unsigned short v;
                if (k2 < KW)      v = ld_bf(Wmat, (size_t)k2 * 2048 + wcol, f32);
                else if (k2 < K1) v = 0;
                else              v = ld_bf(Umat, (size_t)(k2 - K1) * 2048 + wcol, f32);
                Bt[n][k2] = v;
            }
        }
        const float bi  = ld_f(bias, 0 * UU + j0 + gj, f32);
        const float bf_ = ld_f(bias, 1 * UU + j0 + gj, f32);
        const float bg  = ld_f(bias, 2 * UU + j0 + gj, f32);
        const float bo  = ld_f(bias, 3 * UU + j0 + gj, f32);
        __syncthreads();

        const int s_write = (l == 1) ? 1 : 0;
        const int s_read  = (l == 1) ? 0 : 1;
        unsigned short*       Hl  = p.H + (size_t)(s_write * 2 + dir) * seq;
        const unsigned short* Hin = p.H + (size_t)(s_read  * 2 + dir) * seq;

        for (int t = 0; t < TT; ++t) {
            const unsigned short* A1;
            int sA1;
            if (l == 0) {
                int tx = dir ? (TT - 1 - t) : t;
                A1 = p.X + (size_t)tx * BB * EMBP;  sA1 = EMBP;
            } else {
                A1 = Hin + (size_t)t * BB * UU;     sA1 = UU;
            }
            const unsigned short* A2 = Hl + (size_t)(t > 0 ? t - 1 : 0) * BB * UU;
            const int kend = (t == 0) ? K1 : Ktot;   // t==0: h_prev == 0

            const int r0 = wv * 32 + l15;
            const int r1 = r0 + 16;

            f32x4 a0 = {0.f, 0.f, 0.f, 0.f};
            f32x4 a1 = {0.f, 0.f, 0.f, 0.f};
            #pragma unroll 4
            for (int kt = 0; kt < kend; kt += 32) {
                int k2 = kt + quad * 8;              // K1 % 32 == 0
                const unsigned short *ap0, *ap1;
                if (k2 < K1) {
                    ap0 = A1 + (size_t)r0 * sA1 + k2;
                    ap1 = A1 + (size_t)r1 * sA1 + k2;
                } else {
                    ap0 = A2 + (size_t)r0 * UU + (k2 - K1);
                    ap1 = A2 + (size_t)r1 * UU + (k2 - K1);
                }
                bf16x8 bv = *(const bf16x8*)&Bt[l15][k2];
                a0 = __builtin_amdgcn_mfma_f32_16x16x32_bf16(*(const bf16x8*)ap0, bv, a0, 0, 0, 0);
                a1 = __builtin_amdgcn_mfma_f32_16x16x32_bf16(*(const bf16x8*)ap1, bv, a1, 0, 0, 0);
            }
            // D layout: col = lane&15, row = quad*4 + reg  (m89-verified)
            #pragma unroll
            for (int r = 0; r < 4; ++r) {
                zld[wv * 32 +      quad * 4 + r][l15] = a0[r];
                zld[wv * 32 + 16 + quad * 4 + r][l15] = a1[r];
            }
            __syncthreads();

            // ---- gates (fp32, clamped), c in registers, h -> bf16 ----
            {
                float zi = clampz(zld[gr][ 0 + gj] + bi);
                float zf = clampz(zld[gr][ 4 + gj] + bf_);
                float zg = clampz(zld[gr][ 8 + gj] + bg);
                float zo = clampz(zld[gr][12 + gj] + bo);
                float cp = (t == 0) ? 0.0f : c0;
                float cn = sigm(zf) * cp + sigm(zi) * ssign(zg);
                c0 = cn;
                float h = sigm(zo) * ssign(cn);
                Hl[(size_t)t * BB * UU + (size_t)gr * UU + j0 + gj] = f2b(h);
                if (l == 2 && t == TT - 1)
                    p.hf[(size_t)dir * BB * UU + (size_t)gr * UU + j0 + gj] = h;

                int g2 = gr + 64;
                float zi2 = clampz(zld[g2][ 0 + gj] + bi);
                float zf2 = clampz(zld[g2][ 4 + gj] + bf_);
                float zg2 = clampz(zld[g2][ 8 + gj] + bg);
                float zo2 = clampz(zld[g2][12 + gj] + bo);
                float cp2 = (t == 0) ? 0.0f : c1;
                float cn2 = sigm(zf2) * cp2 + sigm(zi2) * ssign(zg2);
                c1 = cn2;
                float h2 = sigm(zo2) * ssign(cn2);
                Hl[(size_t)t * BB * UU + (size_t)g2 * UU + j0 + gj] = f2b(h2);
                if (l == 2 && t == TT - 1)
                    p.hf[(size_t)dir * BB * UU + (size_t)g2 * UU + j0 + gj] = h2;
            }
            gsync(p.flags, ++gen);
        }
    }

    // ---------------- head: block b handles batch row b (all fp32) ----------------
    if (blk < BB) {
        const int b = blk;
        const float* h0 = p.hf + (size_t)b * UU;
        const float* h1 = p.hf + (size_t)BB * UU + (size_t)b * UU;
        float acc = ld_f(p.d0b, tid, f32);
        #pragma unroll 8
        for (int k = 0; k < UU; ++k) {
            float a = 0.5f * (h0[k] + h1[k]);
            acc = fmaf(a, ld_f(p.d0W, (size_t)k * 256 + tid, f32), acc);
        }
        acc = fminf(fmaxf(acc, -1e6f), 1e6f);
        float x = (acc - ld_f(p.bn_mean, tid, f32))
                  * rsqrtf(fmaxf(ld_f(p.bn_var, tid, f32), 0.0f) + 1e-3f)
                  * ld_f(p.bn_gamma, tid, f32) + ld_f(p.bn_beta, tid, f32);
        float al = ld_f(p.alpha, tid, f32);
        hact[tid] = (x > 0.f) ? x : al * x;
        __syncthreads();
        if (tid < 7) {
            float s = ld_f(p.d1b, tid, f32);
            #pragma unroll 8
            for (int k = 0; k < 256; ++k)
                s = fmaf(hact[k], ld_f(p.d1W, k * 7 + tid, f32), s);
            lgts[tid] = fminf(fmaxf(s, -1e6f), 1e6f);
        }
        __syncthreads();
        if (tid == 0) {
            float mx = lgts[0];
            for (int j = 1; j < 7; ++j) mx = fmaxf(mx, lgts[j]);
            float ex[7]; float sum = 0.f;
            for (int j = 0; j < 7; ++j) { ex[j] = __expf(lgts[j] - mx); sum += ex[j]; }
            float inv = 1.0f / sum;
            for (int j = 0; j < 7; ++j) p.out[b * 7 + j] = ex[j] * inv;   // fp32 store
        }
    }
}

extern "C" void kernel_launch(void* const* d_in, const int* in_sizes, int n_in,
                              void* d_out, int out_size, void* d_ws, size_t ws_size,
                              hipStream_t stream) {
    (void)in_sizes; (void)n_in; (void)out_size;

    P p;
    p.ids = (const int*)d_in[0];
    p.emb = d_in[1];
    for (int l = 0; l < 3; ++l) {
        p.Wm[0][l] = d_in[2 + l * 3];
        p.Um[0][l] = d_in[3 + l * 3];
        p.bm[0][l] = d_in[4 + l * 3];
        p.Wm[1][l] = d_in[11 + l * 3];
        p.Um[1][l] = d_in[12 + l * 3];
        p.bm[1][l] = d_in[13 + l * 3];
    }
    p.d0W      = d_in[20];
    p.d0b      = d_in[21];
    p.bn_gamma = d_in[22];
    p.bn_beta  = d_in[23];
    p.bn_mean  = d_in[24];
    p.bn_var   = d_in[25];
    p.alpha    = d_in[26];
    p.d1W      = d_in[27];
    p.d1b      = d_in[28];

    char* base = (ws_size >= NEED_WS || g_pool == nullptr) ? (char*)d_ws : (char*)g_pool;
    const size_t OFF_X  = 4096;                                        // flags: [0,1024)
    const size_t OFF_H  = OFF_X + (size_t)TT * BB * EMBP * 2;          // +10,485,760
    const size_t OFF_HF = OFF_H + (size_t)2 * 2 * TT * BB * UU * 2;    // +67,108,864
    p.flags = (unsigned int*)base;
    p.X     = (unsigned short*)(base + OFF_X);
    p.H     = (unsigned short*)(base + OFF_H);
    p.hf    = (float*)(base + OFF_HF);
    p.out   = (float*)d_out;

    // zero the flag block (gen starts at 1); all other scratch is
    // written-before-read within this launch (poison-safe).
    hipMemsetAsync(base, 0, 4096, stream);
    hipLaunchKernelGGL(bilstm_persistent, dim3(NBLK), dim3(NTHR), 0, stream, p);
}

// Round 7
// 5963.095 us; speedup vs baseline: 2.7995x; 1.5903x over previous
//
#include <hip/hip_runtime.h>
#include <hip/hip_bf16.h>
#include <math.h>

// ---------------- problem constants ----------------
#define TT   128      // timesteps
#define BB   128      // batch
#define UU   512      // LSTM units
#define EMBD 300      // embedding dim
#define EMBP 320      // padded embedding dim (multiple of 32 for MFMA K)
#define NBLK 256
#define NTHR 256

using bf16x8 = __attribute__((ext_vector_type(8))) short;
using f32x4  = __attribute__((ext_vector_type(4))) float;

// ws layout: flags 4KB | X 10MB | H 6 slots x 16MB (write-once!) | hf 512KB
#define NEED_WS 111677440ull
static void* g_pool = nullptr;
__attribute__((constructor)) static void alloc_pool() {
    if (hipMalloc(&g_pool, 120ull * 1024ull * 1024ull) != hipSuccess) g_pool = nullptr;
}

__device__ __forceinline__ float b2f(unsigned short u) {
    union { unsigned int i; float f; } v; v.i = ((unsigned int)u) << 16; return v.f;
}
__device__ __forceinline__ unsigned short f2b(float f) {
    union { unsigned int i; float f; } v; v.f = f;
    unsigned int i = v.i;
    return (unsigned short)((i + 0x7fffu + ((i >> 16) & 1u)) >> 16);  // RNE
}
__device__ __forceinline__ unsigned short ld_bf(const void* p, size_t i, int f32) {
    return f32 ? f2b(((const float*)p)[i]) : ((const unsigned short*)p)[i];
}
__device__ __forceinline__ float ld_f(const void* p, size_t i, int f32) {
    return f32 ? ((const float*)p)[i] : b2f(((const unsigned short*)p)[i]);
}
__device__ __forceinline__ float clampz(float x) {
    return fminf(fmaxf(x, -60.0f), 60.0f);
}
__device__ __forceinline__ float sigm(float x)  { return 1.0f / (1.0f + __expf(-x)); }
__device__ __forceinline__ float ssign(float x) { return x / (1.0f + fabsf(x)); }

__device__ __forceinline__ int detect_f32(const void* emb) {
    const unsigned int* w = (const unsigned int*)emb;
    int cnt = 0;
    #pragma unroll
    for (int i = 0; i < 64; ++i) {
        unsigned int e = (w[i] >> 23) & 0xFFu;
        cnt += (e >= 96u && e <= 159u) ? 1 : 0;
    }
    return cnt >= 48;
}

struct P {
    const int* ids;
    const void* emb;
    const void* Wm[2][3];
    const void* Um[2][3];
    const void* bm[2][3];
    const void *d0W, *d0b;
    const void *bn_gamma, *bn_beta, *bn_mean, *bn_var;
    const void *alpha, *d1W, *d1b;
    unsigned short* X;      // [TT][BB][EMBP] bf16 (written once, fence-full barrier after)
    unsigned short* H;      // [3 slots][2 dirs][TT][BB][UU] bf16 — WRITE-ONCE, write-through
    float* hf;              // [2][BB][UU] fp32 — write-through
    unsigned int* flags;    // [NBLK] per-block generation flags
    float* out;             // [BB][7] fp32
};

// fence-FULL barrier (phase 0 only): X was written with normal cached stores.
__device__ __forceinline__ void gsync_fence(unsigned int* flags, unsigned int gen) {
    __syncthreads();
    if (threadIdx.x == 0) {
        __threadfence();
        __hip_atomic_store(&flags[blockIdx.x], gen, __ATOMIC_RELAXED, __HIP_MEMORY_SCOPE_AGENT);
    }
    if (threadIdx.x < 64) {
        const int i = threadIdx.x;
        for (;;) {
            unsigned int m0 = __hip_atomic_load(&flags[i      ], __ATOMIC_RELAXED, __HIP_MEMORY_SCOPE_AGENT);
            unsigned int m1 = __hip_atomic_load(&flags[i +  64], __ATOMIC_RELAXED, __HIP_MEMORY_SCOPE_AGENT);
            unsigned int m2 = __hip_atomic_load(&flags[i + 128], __ATOMIC_RELAXED, __HIP_MEMORY_SCOPE_AGENT);
            unsigned int m3 = __hip_atomic_load(&flags[i + 192], __ATOMIC_RELAXED, __HIP_MEMORY_SCOPE_AGENT);
            if (__all((m0 >= gen) && (m1 >= gen) && (m2 >= gen) && (m3 >= gen))) break;
            __builtin_amdgcn_s_sleep(1);
        }
        __threadfence();
    }
    __syncthreads();
}

// fence-FREE per-direction barrier. Correct because all inter-block data is
// write-through (agent-scope stores land at the coherent LLC; __syncthreads'
// vmcnt(0) drain orders them before the flag store) and write-once (cached
// reader copies can never be stale).
__device__ __forceinline__ void gsync_dir(unsigned int* flags, int dirbase, unsigned int gen) {
    __syncthreads();
    if (threadIdx.x == 0)
        __hip_atomic_store(&flags[blockIdx.x], gen, __ATOMIC_RELAXED, __HIP_MEMORY_SCOPE_AGENT);
    if (threadIdx.x < 64) {
        const unsigned int* f = flags + dirbase + threadIdx.x;
        for (;;) {
            unsigned int m0 = __hip_atomic_load(f,      __ATOMIC_RELAXED, __HIP_MEMORY_SCOPE_AGENT);
            unsigned int m1 = __hip_atomic_load(f + 64, __ATOMIC_RELAXED, __HIP_MEMORY_SCOPE_AGENT);
            if (__all((m0 >= gen) && (m1 >= gen))) break;
            __builtin_amdgcn_s_sleep(1);
        }
    }
    __syncthreads();
}

// fence-free full-grid barrier (before head: hf is write-through + first-read)
__device__ __forceinline__ void gsync_all(unsigned int* flags, unsigned int gen) {
    __syncthreads();
    if (threadIdx.x == 0)
        __hip_atomic_store(&flags[blockIdx.x], gen, __ATOMIC_RELAXED, __HIP_MEMORY_SCOPE_AGENT);
    if (threadIdx.x < 64) {
        const int i = threadIdx.x;
        for (;;) {
            unsigned int m0 = __hip_atomic_load(&flags[i      ], __ATOMIC_RELAXED, __HIP_MEMORY_SCOPE_AGENT);
            unsigned int m1 = __hip_atomic_load(&flags[i +  64], __ATOMIC_RELAXED, __HIP_MEMORY_SCOPE_AGENT);
            unsigned int m2 = __hip_atomic_load(&flags[i + 128], __ATOMIC_RELAXED, __HIP_MEMORY_SCOPE_AGENT);
            unsigned int m3 = __hip_atomic_load(&flags[i + 192], __ATOMIC_RELAXED, __HIP_MEMORY_SCOPE_AGENT);
            if (__all((m0 >= gen) && (m1 >= gen) && (m2 >= gen) && (m3 >= gen))) break;
            __builtin_amdgcn_s_sleep(1);
        }
    }
    __syncthreads();
}

__global__ __launch_bounds__(NTHR, 1) void bilstm_persistent(P p) {
    const int blk = blockIdx.x;
    const int tid = threadIdx.x;

    const int f32 = detect_f32(p.emb);
    unsigned int gen = 0;

    __shared__ __align__(16) unsigned short Bt[16][1032];  // B panel [n][k] (33 KB)
    __shared__ __align__(16) float zld[128][17];           // z round-trip (8.7 KB)
    __shared__ float hact[256];
    __shared__ float lgts[8];

    // ---------------- phase 0: embedding gather (normal stores) ----------------
    for (int rr = 0; rr < 64; ++rr) {
        int row = blk * 64 + rr;             // row = t*BB + b
        int t = row >> 7, b = row & 127;
        int id = p.ids[b * TT + t];
        unsigned short* xr = p.X + (size_t)row * EMBP;
        for (int k2 = tid; k2 < EMBP; k2 += NTHR)
            xr[k2] = (k2 < EMBD) ? ld_bf(p.emb, (size_t)id * EMBD + k2, f32)
                                 : (unsigned short)0;
    }
    gsync_fence(p.flags, ++gen);             // only fence-full barrier in the kernel

    // block responsibilities: dir, 4 h-columns, full batch M=128
    const int dir     = blk >> 7;
    const int dirbase = dir << 7;
    const int j0      = (blk & 127) * 4;

    const int wv   = tid >> 6;               // wave 0..3
    const int lane = tid & 63;
    const int l15  = lane & 15;
    const int quad = lane >> 4;

    const int r_   = tid & 127;              // gate thread: row r_, 2 adjacent cols
    const int half = tid >> 7;               //   cols j0+2*half, j0+2*half+1
    const int jA   = 2 * half;

    float cA = 0.0f, cB = 0.0f;              // cell state in registers

    const size_t seq = (size_t)TT * BB * UU;

    for (int l = 0; l < 3; ++l) {
        const int KW   = (l == 0) ? EMBD : UU;
        const int K1   = (l == 0) ? EMBP : UU;
        const int Ktot = K1 + UU;
        const void* Wmat = p.Wm[dir][l];
        const void* Umat = p.Um[dir][l];
        const void* bias = p.bm[dir][l];

        // ---- stage B panel (16 gate-columns) into LDS as bf16 ----
        {
            int n = tid >> 4, ks = tid & 15;
            int wcol = (n >> 2) * UU + j0 + (n & 3);   // gate*512 + j
            for (int k2 = ks; k2 < Ktot; k2 += 16) {
                unsigned short v;
                if (k2 < KW)      v = ld_bf(Wmat, (size_t)k2 * 2048 + wcol, f32);
                else if (k2 < K1) v = 0;
                else              v = ld_bf(Umat, (size_t)(k2 - K1) * 2048 + wcol, f32);
                Bt[n][k2] = v;
            }
        }
        float bzA[4], bzB[4];
        #pragma unroll
        for (int g = 0; g < 4; ++g) {
            bzA[g] = ld_f(bias, g * UU + j0 + jA,     f32);
            bzB[g] = ld_f(bias, g * UU + j0 + jA + 1, f32);
        }
        __syncthreads();

        // write-once slots: layer l writes slot l, reads slot l-1
        unsigned short*       Hl  = p.H + (size_t)(l * 2 + dir) * seq;
        const unsigned short* Hin = (l > 0) ? (p.H + (size_t)((l - 1) * 2 + dir) * seq) : nullptr;

        for (int t = 0; t < TT; ++t) {
            const unsigned short* A1;
            int sA1;
            if (l == 0) {
                int tx = dir ? (TT - 1 - t) : t;
                A1 = p.X + (size_t)tx * BB * EMBP;  sA1 = EMBP;
            } else {
                A1 = Hin + (size_t)t * BB * UU;     sA1 = UU;
            }

            const int r0 = wv * 32 + l15;
            const int r1 = r0 + 16;
            const int ko = quad * 8;

            f32x4 a0 = {0.f, 0.f, 0.f, 0.f};
            f32x4 a1 = {0.f, 0.f, 0.f, 0.f};

            {   // input contribution: A1 (x or h from layer below)
                const unsigned short* ap0 = A1 + (size_t)r0 * sA1 + ko;
                const unsigned short* ap1 = A1 + (size_t)r1 * sA1 + ko;
                const unsigned short* bp  = &Bt[l15][ko];
                for (int kt = 0; kt < K1; kt += 32) {
                    bf16x8 bv = *(const bf16x8*)(bp + kt);
                    a0 = __builtin_amdgcn_mfma_f32_16x16x32_bf16(*(const bf16x8*)(ap0 + kt), bv, a0, 0, 0, 0);
                    a1 = __builtin_amdgcn_mfma_f32_16x16x32_bf16(*(const bf16x8*)(ap1 + kt), bv, a1, 0, 0, 0);
                }
            }
            if (t > 0) {   // recurrent contribution: A2 = Hl[t-1]
                const unsigned short* A2 = Hl + (size_t)(t - 1) * BB * UU;
                const unsigned short* ap0 = A2 + (size_t)r0 * UU + ko;
                const unsigned short* ap1 = A2 + (size_t)r1 * UU + ko;
                const unsigned short* bp  = &Bt[l15][K1 + ko];
                for (int kt = 0; kt < UU; kt += 32) {
                    bf16x8 bv = *(const bf16x8*)(bp + kt);
                    a0 = __builtin_amdgcn_mfma_f32_16x16x32_bf16(*(const bf16x8*)(ap0 + kt), bv, a0, 0, 0, 0);
                    a1 = __builtin_amdgcn_mfma_f32_16x16x32_bf16(*(const bf16x8*)(ap1 + kt), bv, a1, 0, 0, 0);
                }
            }
            // D layout: col = lane&15, row = quad*4 + reg  (m89-verified)
            #pragma unroll
            for (int r = 0; r < 4; ++r) {
                zld[wv * 32 +      quad * 4 + r][l15] = a0[r];
                zld[wv * 32 + 16 + quad * 4 + r][l15] = a1[r];
            }
            __syncthreads();

            // ---- gates (fp32, clamped); one row x two cols per thread ----
            {
                float ziA = clampz(zld[r_][ 0 + jA] + bzA[0]);
                float zfA = clampz(zld[r_][ 4 + jA] + bzA[1]);
                float zgA = clampz(zld[r_][ 8 + jA] + bzA[2]);
                float zoA = clampz(zld[r_][12 + jA] + bzA[3]);
                float ziB = clampz(zld[r_][ 1 + jA] + bzB[0]);
                float zfB = clampz(zld[r_][ 5 + jA] + bzB[1]);
                float zgB = clampz(zld[r_][ 9 + jA] + bzB[2]);
                float zoB = clampz(zld[r_][13 + jA] + bzB[3]);
                float cpA = (t == 0) ? 0.0f : cA;
                float cpB = (t == 0) ? 0.0f : cB;
                float cnA = sigm(zfA) * cpA + sigm(ziA) * ssign(zgA);
                float cnB = sigm(zfB) * cpB + sigm(ziB) * ssign(zgB);
                cA = cnA; cB = cnB;
                float hA = sigm(zoA) * ssign(cnA);
                float hB = sigm(zoB) * ssign(cnB);
                // packed write-through store (device-coherent; never dirty in L2)
                unsigned int pk = (unsigned int)f2b(hA) | ((unsigned int)f2b(hB) << 16);
                __hip_atomic_store((unsigned int*)&Hl[(size_t)t * BB * UU + (size_t)r_ * UU + j0 + jA],
                                   pk, __ATOMIC_RELAXED, __HIP_MEMORY_SCOPE_AGENT);
                if (l == 2 && t == TT - 1) {
                    size_t o = (size_t)dir * BB * UU + (size_t)r_ * UU + j0 + jA;
                    __hip_atomic_store(&p.hf[o],     hA, __ATOMIC_RELAXED, __HIP_MEMORY_SCOPE_AGENT);
                    __hip_atomic_store(&p.hf[o + 1], hB, __ATOMIC_RELAXED, __HIP_MEMORY_SCOPE_AGENT);
                }
            }
            gsync_dir(p.flags, dirbase, ++gen);
        }
    }

    gsync_all(p.flags, ++gen);   // both dirs' hf complete before head

    // ---------------- head: block b handles batch row b (all fp32) ----------------
    if (blk < BB) {
        const int b = blk;
        const float* h0 = p.hf + (size_t)b * UU;
        const float* h1 = p.hf + (size_t)BB * UU + (size_t)b * UU;
        float acc = ld_f(p.d0b, tid, f32);
        #pragma unroll 8
        for (int k = 0; k < UU; ++k) {
            float a = 0.5f * (h0[k] + h1[k]);
            acc = fmaf(a, ld_f(p.d0W, (size_t)k * 256 + tid, f32), acc);
        }
        acc = fminf(fmaxf(acc, -1e6f), 1e6f);
        float x = (acc - ld_f(p.bn_mean, tid, f32))
                  * rsqrtf(fmaxf(ld_f(p.bn_var, tid, f32), 0.0f) + 1e-3f)
                  * ld_f(p.bn_gamma, tid, f32) + ld_f(p.bn_beta, tid, f32);
        float al = ld_f(p.alpha, tid, f32);
        hact[tid] = (x > 0.f) ? x : al * x;
        __syncthreads();
        if (tid < 7) {
            float s = ld_f(p.d1b, tid, f32);
            #pragma unroll 8
            for (int k = 0; k < 256; ++k)
                s = fmaf(hact[k], ld_f(p.d1W, k * 7 + tid, f32), s);
            lgts[tid] = fminf(fmaxf(s, -1e6f), 1e6f);
        }
        __syncthreads();
        if (tid == 0) {
            float mx = lgts[0];
            for (int j = 1; j < 7; ++j) mx = fmaxf(mx, lgts[j]);
            float ex[7]; float sum = 0.f;
            for (int j = 0; j < 7; ++j) { ex[j] = __expf(lgts[j] - mx); sum += ex[j]; }
            float inv = 1.0f / sum;
            for (int j = 0; j < 7; ++j) p.out[b * 7 + j] = ex[j] * inv;
        }
    }
}

extern "C" void kernel_launch(void* const* d_in, const int* in_sizes, int n_in,
                              void* d_out, int out_size, void* d_ws, size_t ws_size,
                              hipStream_t stream) {
    (void)in_sizes; (void)n_in; (void)out_size;

    P p;
    p.ids = (const int*)d_in[0];
    p.emb = d_in[1];
    for (int l = 0; l < 3; ++l) {
        p.Wm[0][l] = d_in[2 + l * 3];
        p.Um[0][l] = d_in[3 + l * 3];
        p.bm[0][l] = d_in[4 + l * 3];
        p.Wm[1][l] = d_in[11 + l * 3];
        p.Um[1][l] = d_in[12 + l * 3];
        p.bm[1][l] = d_in[13 + l * 3];
    }
    p.d0W      = d_in[20];
    p.d0b      = d_in[21];
    p.bn_gamma = d_in[22];
    p.bn_beta  = d_in[23];
    p.bn_mean  = d_in[24];
    p.bn_var   = d_in[25];
    p.alpha    = d_in[26];
    p.d1W      = d_in[27];
    p.d1b      = d_in[28];

    char* base = (ws_size >= NEED_WS || g_pool == nullptr) ? (char*)d_ws : (char*)g_pool;
    const size_t OFF_X  = 4096;                                        // flags
    const size_t OFF_H  = OFF_X + (size_t)TT * BB * EMBP * 2;          // +10,485,760
    const size_t OFF_HF = OFF_H + (size_t)3 * 2 * TT * BB * UU * 2;    // +100,663,296
    p.flags = (unsigned int*)base;
    p.X     = (unsigned short*)(base + OFF_X);
    p.H     = (unsigned short*)(base + OFF_H);
    p.hf    = (float*)(base + OFF_HF);
    p.out   = (float*)d_out;

    hipMemsetAsync(base, 0, 4096, stream);   // flags only; rest is write-before-read
    hipLaunchKernelGGL(bilstm_persistent, dim3(NBLK), dim3(NTHR), 0, stream, p);
}

// Round 8
// 4366.277 us; speedup vs baseline: 3.8233x; 1.3657x over previous
//
#include <hip/hip_runtime.h>
#include <hip/hip_bf16.h>
#include <math.h>

// ---------------- problem constants ----------------
#define TT   128      // timesteps
#define BB   128      // batch
#define UU   512      // LSTM units
#define EMBD 300      // embedding dim
#define EMBP 320      // padded embedding dim (multiple of 32 for MFMA K)
#define NBLK 256
#define NTHR 256

using bf16x8 = __attribute__((ext_vector_type(8))) short;
using f32x4  = __attribute__((ext_vector_type(4))) float;

// ws layout: flags/epoch 4KB | X 10MB | H 6 slots x 16MB (write-once!) | hf 512KB
#define NEED_WS 111677440ull
static void* g_pool = nullptr;
__attribute__((constructor)) static void alloc_pool() {
    if (hipMalloc(&g_pool, 120ull * 1024ull * 1024ull) != hipSuccess) g_pool = nullptr;
}

__device__ __forceinline__ float b2f(unsigned short u) {
    union { unsigned int i; float f; } v; v.i = ((unsigned int)u) << 16; return v.f;
}
__device__ __forceinline__ unsigned short f2b(float f) {
    union { unsigned int i; float f; } v; v.f = f;
    unsigned int i = v.i;
    return (unsigned short)((i + 0x7fffu + ((i >> 16) & 1u)) >> 16);  // RNE
}
__device__ __forceinline__ unsigned short ld_bf(const void* p, size_t i, int f32) {
    return f32 ? f2b(((const float*)p)[i]) : ((const unsigned short*)p)[i];
}
__device__ __forceinline__ float ld_f(const void* p, size_t i, int f32) {
    return f32 ? ((const float*)p)[i] : b2f(((const unsigned short*)p)[i]);
}
__device__ __forceinline__ float clampz(float x) {
    return fminf(fmaxf(x, -60.0f), 60.0f);
}
__device__ __forceinline__ float sigm(float x)  { return 1.0f / (1.0f + __expf(-x)); }
__device__ __forceinline__ float ssign(float x) { return x / (1.0f + fabsf(x)); }

__device__ __forceinline__ int detect_f32(const void* emb) {
    const unsigned int* w = (const unsigned int*)emb;
    int cnt = 0;
    #pragma unroll
    for (int i = 0; i < 64; ++i) {
        unsigned int e = (w[i] >> 23) & 0xFFu;
        cnt += (e >= 96u && e <= 159u) ? 1 : 0;
    }
    return cnt >= 48;
}

struct P {
    const int* ids;
    const void* emb;
    const void* Wm[2][3];
    const void* Um[2][3];
    const void* bm[2][3];
    const void *d0W, *d0b;
    const void *bn_gamma, *bn_beta, *bn_mean, *bn_var;
    const void *alpha, *d1W, *d1b;
    unsigned short* X;      // [TT][BB][EMBP] bf16 (written once, fence-full barrier after)
    unsigned short* H;      // [3 slots][2 dirs][TT][BB][UU] bf16 — WRITE-ONCE, write-through
    float* hf;              // [2][BB][UU] fp32 — write-through
    unsigned int* flags;    // [NBLK] per-block generation flags
    unsigned int* epoch;    // epoch[0]=dir0, epoch[64]=dir1 (separate lines)
    float* out;             // [BB][7] fp32
};

#define EPOFF 64   // dir1 epoch word offset (256 B from dir0)

__device__ __forceinline__ unsigned int ald(const unsigned int* a) {
    return __hip_atomic_load(a, __ATOMIC_RELAXED, __HIP_MEMORY_SCOPE_AGENT);
}
__device__ __forceinline__ void ast(unsigned int* a, unsigned int v) {
    __hip_atomic_store(a, v, __ATOMIC_RELAXED, __HIP_MEMORY_SCOPE_AGENT);
}

// fence-FULL flat barrier (phase 0 only; X uses normal cached stores)
__device__ __forceinline__ void gsync_fence(unsigned int* flags, unsigned int gen) {
    __syncthreads();
    if (threadIdx.x == 0) {
        __threadfence();
        ast(&flags[blockIdx.x], gen);
    }
    if (threadIdx.x < 64) {
        const int i = threadIdx.x;
        for (;;) {
            bool ok = (ald(&flags[i]) >= gen) && (ald(&flags[i + 64]) >= gen) &&
                      (ald(&flags[i + 128]) >= gen) && (ald(&flags[i + 192]) >= gen);
            if (__all(ok)) break;
            __builtin_amdgcn_s_sleep(1);
        }
        __threadfence();
    }
    __syncthreads();
}

// Two-level aggregated per-direction barrier (fence-free; data is
// write-through + write-once). Leaves store own flag; the direction's
// aggregator block polls its 128 flags and publishes one epoch word;
// everyone polls that single word (same-address broadcast load).
__device__ __forceinline__ void gsync_dir(P& p, int dirbase, int isagg, unsigned int gen) {
    __syncthreads();
    if (threadIdx.x == 0)
        ast(&p.flags[blockIdx.x], gen);
    if (isagg && threadIdx.x < 64) {
        const unsigned int* f = p.flags + dirbase + threadIdx.x;
        for (;;) {
            if (__all((ald(f) >= gen) && (ald(f + 64) >= gen))) break;
            __builtin_amdgcn_s_sleep(1);
        }
        if (threadIdx.x == 0)
            ast(&p.epoch[dirbase >> 1], gen);   // 0 -> epoch[0], 128 -> epoch[64]
    }
    if (threadIdx.x < 64) {
        const unsigned int* e = &p.epoch[dirbase >> 1];
        while (ald(e) < gen) __builtin_amdgcn_s_sleep(1);
    }
    __syncthreads();
}

// full-grid aggregated barrier (before head)
__device__ __forceinline__ void gsync_all(P& p, int dirbase, int isagg, unsigned int gen) {
    __syncthreads();
    if (threadIdx.x == 0)
        ast(&p.flags[blockIdx.x], gen);
    if (isagg && threadIdx.x < 64) {
        const unsigned int* f = p.flags + dirbase + threadIdx.x;
        for (;;) {
            if (__all((ald(f) >= gen) && (ald(f + 64) >= gen))) break;
            __builtin_amdgcn_s_sleep(1);
        }
        if (threadIdx.x == 0)
            ast(&p.epoch[dirbase >> 1], gen);
    }
    if (threadIdx.x < 64) {
        while (!((ald(&p.epoch[0]) >= gen) && (ald(&p.epoch[EPOFF]) >= gen)))
            __builtin_amdgcn_s_sleep(1);
    }
    __syncthreads();
}

__global__ __launch_bounds__(NTHR, 1) void bilstm_persistent(P p) {
    const int blk = blockIdx.x;
    const int tid = threadIdx.x;

    const int f32 = detect_f32(p.emb);
    unsigned int gen = 0;

    __shared__ __align__(16) unsigned short Bt[16][1032];  // B panel [n][k] (33 KB)
    __shared__ __align__(16) float zld[128][17];           // z round-trip (8.7 KB)
    __shared__ float hact[256];
    __shared__ float lgts[8];

    // ---------------- phase 0: embedding gather (normal stores) ----------------
    for (int rr = 0; rr < 64; ++rr) {
        int row = blk * 64 + rr;             // row = t*BB + b
        int t = row >> 7, b = row & 127;
        int id = p.ids[b * TT + t];
        unsigned short* xr = p.X + (size_t)row * EMBP;
        for (int k2 = tid; k2 < EMBP; k2 += NTHR)
            xr[k2] = (k2 < EMBD) ? ld_bf(p.emb, (size_t)id * EMBD + k2, f32)
                                 : (unsigned short)0;
    }
    gsync_fence(p.flags, ++gen);             // only fence-full barrier in the kernel

    // block responsibilities: dir, 4 h-columns, full batch M=128
    const int dir     = blk >> 7;
    const int dirbase = dir << 7;
    const int isagg   = (blk == dirbase);
    const int j0      = (blk & 127) * 4;

    const int wv   = tid >> 6;               // wave 0..3
    const int lane = tid & 63;
    const int l15  = lane & 15;
    const int quad = lane >> 4;

    const int r_   = tid & 127;              // gate thread: row r_, 2 adjacent cols
    const int half = tid >> 7;               //   cols j0+2*half, j0+2*half+1
    const int jA   = 2 * half;

    float cA = 0.0f, cB = 0.0f;              // cell state in registers

    const size_t seq = (size_t)TT * BB * UU;

    for (int l = 0; l < 3; ++l) {
        const int KW   = (l == 0) ? EMBD : UU;
        const int K1   = (l == 0) ? EMBP : UU;
        const int Ktot = K1 + UU;
        const void* Wmat = p.Wm[dir][l];
        const void* Umat = p.Um[dir][l];
        const void* bias = p.bm[dir][l];

        // ---- stage B panel (16 gate-columns) into LDS as bf16 ----
        {
            int n = tid >> 4, ks = tid & 15;
            int wcol = (n >> 2) * UU + j0 + (n & 3);   // gate*512 + j
            for (int k2 = ks; k2 < Ktot; k2 += 16) {
                unsigned short v;
                if (k2 < KW)      v = ld_bf(Wmat, (size_t)k2 * 2048 + wcol, f32);
                else if (k2 < K1) v = 0;
                else              v = ld_bf(Umat, (size_t)(k2 - K1) * 2048 + wcol, f32);
                Bt[n][k2] = v;
            }
        }
        float bzA[4], bzB[4];
        #pragma unroll
        for (int g = 0; g < 4; ++g) {
            bzA[g] = ld_f(bias, g * UU + j0 + jA,     f32);
            bzB[g] = ld_f(bias, g * UU + j0 + jA + 1, f32);
        }
        __syncthreads();

        // write-once slots: layer l writes slot l, reads slot l-1
        unsigned short*       Hl  = p.H + (size_t)(l * 2 + dir) * seq;
        const unsigned short* Hin = (l > 0) ? (p.H + (size_t)((l - 1) * 2 + dir) * seq) : nullptr;

        for (int t = 0; t < TT; ++t) {
            const unsigned short* A1;
            int sA1;
            if (l == 0) {
                int tx = dir ? (TT - 1 - t) : t;
                A1 = p.X + (size_t)tx * BB * EMBP;  sA1 = EMBP;
            } else {
                A1 = Hin + (size_t)t * BB * UU;     sA1 = UU;
            }

            const int r0 = wv * 32 + l15;
            const int r1 = r0 + 16;
            const int ko = quad * 8;

            f32x4 a0 = {0.f, 0.f, 0.f, 0.f};
            f32x4 a1 = {0.f, 0.f, 0.f, 0.f};

            {   // input contribution: A1 (x or h from layer below)
                const unsigned short* ap0 = A1 + (size_t)r0 * sA1 + ko;
                const unsigned short* ap1 = A1 + (size_t)r1 * sA1 + ko;
                const unsigned short* bp  = &Bt[l15][ko];
                for (int kt = 0; kt < K1; kt += 32) {
                    bf16x8 bv = *(const bf16x8*)(bp + kt);
                    a0 = __builtin_amdgcn_mfma_f32_16x16x32_bf16(*(const bf16x8*)(ap0 + kt), bv, a0, 0, 0, 0);
                    a1 = __builtin_amdgcn_mfma_f32_16x16x32_bf16(*(const bf16x8*)(ap1 + kt), bv, a1, 0, 0, 0);
                }
            }
            if (t > 0) {   // recurrent contribution: A2 = Hl[t-1]
                const unsigned short* A2 = Hl + (size_t)(t - 1) * BB * UU;
                const unsigned short* ap0 = A2 + (size_t)r0 * UU + ko;
                const unsigned short* ap1 = A2 + (size_t)r1 * UU + ko;
                const unsigned short* bp  = &Bt[l15][K1 + ko];
                for (int kt = 0; kt < UU; kt += 32) {
                    bf16x8 bv = *(const bf16x8*)(bp + kt);
                    a0 = __builtin_amdgcn_mfma_f32_16x16x32_bf16(*(const bf16x8*)(ap0 + kt), bv, a0, 0, 0, 0);
                    a1 = __builtin_amdgcn_mfma_f32_16x16x32_bf16(*(const bf16x8*)(ap1 + kt), bv, a1, 0, 0, 0);
                }
            }
            // D layout: col = lane&15, row = quad*4 + reg  (m89-verified)
            #pragma unroll
            for (int r = 0; r < 4; ++r) {
                zld[wv * 32 +      quad * 4 + r][l15] = a0[r];
                zld[wv * 32 + 16 + quad * 4 + r][l15] = a1[r];
            }
            __syncthreads();

            // ---- gates (fp32, clamped); one row x two cols per thread ----
            {
                float ziA = clampz(zld[r_][ 0 + jA] + bzA[0]);
                float zfA = clampz(zld[r_][ 4 + jA] + bzA[1]);
                float zgA = clampz(zld[r_][ 8 + jA] + bzA[2]);
                float zoA = clampz(zld[r_][12 + jA] + bzA[3]);
                float ziB = clampz(zld[r_][ 1 + jA] + bzB[0]);
                float zfB = clampz(zld[r_][ 5 + jA] + bzB[1]);
                float zgB = clampz(zld[r_][ 9 + jA] + bzB[2]);
                float zoB = clampz(zld[r_][13 + jA] + bzB[3]);
                float cpA = (t == 0) ? 0.0f : cA;
                float cpB = (t == 0) ? 0.0f : cB;
                float cnA = sigm(zfA) * cpA + sigm(ziA) * ssign(zgA);
                float cnB = sigm(zfB) * cpB + sigm(ziB) * ssign(zgB);
                cA = cnA; cB = cnB;
                float hA = sigm(zoA) * ssign(cnA);
                float hB = sigm(zoB) * ssign(cnB);
                // packed write-through store (device-coherent; never dirty in L2)
                unsigned int pk = (unsigned int)f2b(hA) | ((unsigned int)f2b(hB) << 16);
                __hip_atomic_store((unsigned int*)&Hl[(size_t)t * BB * UU + (size_t)r_ * UU + j0 + jA],
                                   pk, __ATOMIC_RELAXED, __HIP_MEMORY_SCOPE_AGENT);
                if (l == 2 && t == TT - 1) {
                    size_t o = (size_t)dir * BB * UU + (size_t)r_ * UU + j0 + jA;
                    __hip_atomic_store(&p.hf[o],     hA, __ATOMIC_RELAXED, __HIP_MEMORY_SCOPE_AGENT);
                    __hip_atomic_store(&p.hf[o + 1], hB, __ATOMIC_RELAXED, __HIP_MEMORY_SCOPE_AGENT);
                }
            }
            gsync_dir(p, dirbase, isagg, ++gen);
        }
    }

    gsync_all(p, dirbase, isagg, ++gen);   // both dirs' hf complete before head

    // ---------------- head: block b handles batch row b (all fp32) ----------------
    if (blk < BB) {
        const int b = blk;
        const float* h0 = p.hf + (size_t)b * UU;
        const float* h1 = p.hf + (size_t)BB * UU + (size_t)b * UU;
        float acc = ld_f(p.d0b, tid, f32);
        #pragma unroll 8
        for (int k = 0; k < UU; ++k) {
            float a = 0.5f * (h0[k] + h1[k]);
            acc = fmaf(a, ld_f(p.d0W, (size_t)k * 256 + tid, f32), acc);
        }
        acc = fminf(fmaxf(acc, -1e6f), 1e6f);
        float x = (acc - ld_f(p.bn_mean, tid, f32))
                  * rsqrtf(fmaxf(ld_f(p.bn_var, tid, f32), 0.0f) + 1e-3f)
                  * ld_f(p.bn_gamma, tid, f32) + ld_f(p.bn_beta, tid, f32);
        float al = ld_f(p.alpha, tid, f32);
        hact[tid] = (x > 0.f) ? x : al * x;
        __syncthreads();
        if (tid < 7) {
            float s = ld_f(p.d1b, tid, f32);
            #pragma unroll 8
            for (int k = 0; k < 256; ++k)
                s = fmaf(hact[k], ld_f(p.d1W, k * 7 + tid, f32), s);
            lgts[tid] = fminf(fmaxf(s, -1e6f), 1e6f);
        }
        __syncthreads();
        if (tid == 0) {
            float mx = lgts[0];
            for (int j = 1; j < 7; ++j) mx = fmaxf(mx, lgts[j]);
            float ex[7]; float sum = 0.f;
            for (int j = 0; j < 7; ++j) { ex[j] = __expf(lgts[j] - mx); sum += ex[j]; }
            float inv = 1.0f / sum;
            for (int j = 0; j < 7; ++j) p.out[b * 7 + j] = ex[j] * inv;
        }
    }
}

extern "C" void kernel_launch(void* const* d_in, const int* in_sizes, int n_in,
                              void* d_out, int out_size, void* d_ws, size_t ws_size,
                              hipStream_t stream) {
    (void)in_sizes; (void)n_in; (void)out_size;

    P p;
    p.ids = (const int*)d_in[0];
    p.emb = d_in[1];
    for (int l = 0; l < 3; ++l) {
        p.Wm[0][l] = d_in[2 + l * 3];
        p.Um[0][l] = d_in[3 + l * 3];
        p.bm[0][l] = d_in[4 + l * 3];
        p.Wm[1][l] = d_in[11 + l * 3];
        p.Um[1][l] = d_in[12 + l * 3];
        p.bm[1][l] = d_in[13 + l * 3];
    }
    p.d0W      = d_in[20];
    p.d0b      = d_in[21];
    p.bn_gamma = d_in[22];
    p.bn_beta  = d_in[23];
    p.bn_mean  = d_in[24];
    p.bn_var   = d_in[25];
    p.alpha    = d_in[26];
    p.d1W      = d_in[27];
    p.d1b      = d_in[28];

    char* base = (ws_size >= NEED_WS || g_pool == nullptr) ? (char*)d_ws : (char*)g_pool;
    const size_t OFF_X  = 4096;                                        // flags@0, epoch@2048
    const size_t OFF_H  = OFF_X + (size_t)TT * BB * EMBP * 2;          // +10,485,760
    const size_t OFF_HF = OFF_H + (size_t)3 * 2 * TT * BB * UU * 2;    // +100,663,296
    p.flags = (unsigned int*)base;
    p.epoch = (unsigned int*)(base + 2048);
    p.X     = (unsigned short*)(base + OFF_X);
    p.H     = (unsigned short*)(base + OFF_H);
    p.hf    = (float*)(base + OFF_HF);
    p.out   = (float*)d_out;

    hipMemsetAsync(base, 0, 4096, stream);   // flags+epoch; rest write-before-read
    hipLaunchKernelGGL(bilstm_persistent, dim3(NBLK), dim3(NTHR), 0, stream, p);
}